// Round 3
// baseline (407.005 us; speedup 1.0000x reference)
//
#include <hip/hip_runtime.h>
#include <hip/hip_bf16.h>

// DQNNetwork: M=65536 stocks, K=768 features, N=512 hidden, 3 actions.
// ALL inputs and the output are FP32 (per reference dtypes).
//   h = relu(X @ Wh^T + bh)                        [M,N]
//   out[i,a] = relu( sum_g h[i,g]*(Wf[a,g] - Wf[a,512+g]/(M-1)) + bf[a]
//                    + (sum_g colsum[g]*Wf[a,512+g])/(M-1) )
// colsum = column sums of h. Second GEMM collapses to a 3-vector dot per row.
// Compute path: fp32 -> bf16 (RNE) -> MFMA with fp32 accumulation.

#define M_DIM 65536
#define K_DIM 768
#define N_DIM 512
#define INV_NM1 (1.0f / 65535.0f)

typedef __attribute__((ext_vector_type(8))) short shortx8;   // 8 bf16 (4 VGPRs)
typedef __attribute__((ext_vector_type(4))) short shortx4;   // 4 bf16 (2 VGPRs)
typedef __attribute__((ext_vector_type(4))) float floatx4;   // MFMA C/D

__device__ __forceinline__ unsigned short f2b(float f) {
    unsigned u = __float_as_uint(f);
    unsigned r = (u + 0x7fffu + ((u >> 16) & 1u)) >> 16;   // RNE
    return (unsigned short)r;
}

// ---------------------------------------------------------------------------
// Kernel 1: h = relu(X @ Wh^T + bh) [M,N] -> bf16 H + fp32 column sums.
// 128x128 C-tile, 256 threads = 4 waves (2x2 of 64x64), BK=64,
// mfma_f32_16x16x32_bf16. fp32 global loads, convert-to-bf16 in staging.
// ---------------------------------------------------------------------------
__global__ __launch_bounds__(256) void gemm_h_kernel(
    const float* __restrict__ X,     // [M,K] fp32
    const float* __restrict__ Wh,    // [N,K] fp32 (already B^T layout)
    const float* __restrict__ bh,    // [N] fp32
    unsigned short* __restrict__ Hout,  // [M,N] bf16
    float* __restrict__ colsum)      // [N] fp32, pre-zeroed
{
    __shared__ unsigned short As[128 * 64];  // 16 KB bf16
    __shared__ unsigned short Bs[128 * 64];  // 16 KB bf16

    const int tid  = threadIdx.x;
    const int wave = tid >> 6;
    const int lane = tid & 63;
    const int l16  = lane & 15;
    const int quad = lane >> 4;
    const int wm   = wave >> 1;   // wave's 64-row block
    const int wn   = wave & 1;    // wave's 64-col block

    const int n0 = blockIdx.x * 128;
    const int m0 = blockIdx.y * 128;

    floatx4 acc[4][4];
    #pragma unroll
    for (int i = 0; i < 4; i++)
        #pragma unroll
        for (int j = 0; j < 4; j++) {
            floatx4 z = {0.f, 0.f, 0.f, 0.f};
            acc[i][j] = z;
        }

    for (int k0 = 0; k0 < K_DIM; k0 += 64) {
        // Stage 128x64 fp32 tiles of X and Wh as bf16 into LDS [128][64].
        // Chunk = float4 (16B load, 4 elems). 2048 chunks/tile, 8 passes.
        #pragma unroll
        for (int p = 0; p < 8; p++) {
            const int c   = p * 256 + tid;       // 0..2047
            const int row = c >> 4;              // 0..127
            const int f4  = (c & 15) << 2;       // elem offset in row: 0..60
            const float4 av = *(const float4*)(X  + (size_t)(m0 + row) * K_DIM + k0 + f4);
            const float4 bv = *(const float4*)(Wh + (size_t)(n0 + row) * K_DIM + k0 + f4);
            shortx4 a4, b4;
            a4.x = (short)f2b(av.x); a4.y = (short)f2b(av.y);
            a4.z = (short)f2b(av.z); a4.w = (short)f2b(av.w);
            b4.x = (short)f2b(bv.x); b4.y = (short)f2b(bv.y);
            b4.z = (short)f2b(bv.z); b4.w = (short)f2b(bv.w);
            *(shortx4*)(As + row * 64 + f4) = a4;
            *(shortx4*)(Bs + row * 64 + f4) = b4;
        }
        __syncthreads();

        #pragma unroll
        for (int kk = 0; kk < 64; kk += 32) {
            // A-frag: lane holds A[m=l16][k=quad*8+j]; B symmetric (B^T conv).
            shortx8 afrag[4], bfrag[4];
            const int kof = kk + quad * 8;
            #pragma unroll
            for (int mt = 0; mt < 4; mt++)
                afrag[mt] = *(const shortx8*)(As + (wm * 64 + mt * 16 + l16) * 64 + kof);
            #pragma unroll
            for (int nt = 0; nt < 4; nt++)
                bfrag[nt] = *(const shortx8*)(Bs + (wn * 64 + nt * 16 + l16) * 64 + kof);
            #pragma unroll
            for (int mt = 0; mt < 4; mt++)
                #pragma unroll
                for (int nt = 0; nt < 4; nt++)
                    acc[mt][nt] = __builtin_amdgcn_mfma_f32_16x16x32_bf16(
                        afrag[mt], bfrag[nt], acc[mt][nt], 0, 0, 0);
        }
        __syncthreads();
    }

    // Epilogue. C/D layout: col = lane&15, row = quad*4 + reg (m89-verified).
    float bhv[4];
    #pragma unroll
    for (int nt = 0; nt < 4; nt++)
        bhv[nt] = bh[n0 + wn * 64 + nt * 16 + l16];

    float cs[4] = {0.f, 0.f, 0.f, 0.f};
    #pragma unroll
    for (int mt = 0; mt < 4; mt++) {
        #pragma unroll
        for (int nt = 0; nt < 4; nt++) {
            const int col = n0 + wn * 64 + nt * 16 + l16;
            #pragma unroll
            for (int rg = 0; rg < 4; rg++) {
                const int row = m0 + wm * 64 + mt * 16 + quad * 4 + rg;
                float v = acc[mt][nt][rg] + bhv[nt];
                v = v > 0.f ? v : 0.f;
                Hout[(size_t)row * N_DIM + col] = f2b(v);
                cs[nt] += v;
            }
        }
    }
    // Same column lives in lanes {l16, l16+16, l16+32, l16+48}.
    #pragma unroll
    for (int nt = 0; nt < 4; nt++) {
        float v = cs[nt];
        v += __shfl_xor(v, 16, 64);
        v += __shfl_xor(v, 32, 64);
        if (lane < 16)
            atomicAdd(&colsum[n0 + wn * 64 + nt * 16 + l16], v);
    }
}

// ---------------------------------------------------------------------------
// Kernel 2: out[i,a] = relu( dot(h[i,:], W'[a,:]) + c[a] ), fp32 out.
// One wave per row: 64 lanes x 8 bf16 = 512 elems, coalesced uint4 loads.
// W'[a,g] = Wf[a,g] - Wf[a,512+g]/65535 held in registers (8 g's/lane).
// ---------------------------------------------------------------------------
__global__ __launch_bounds__(256) void head_kernel(
    const unsigned short* __restrict__ H,   // [M,512] bf16
    const float* __restrict__ Wf,           // [3,1024] fp32
    const float* __restrict__ bfb,          // [3] fp32
    const float* __restrict__ colsum,       // [512] fp32
    float* __restrict__ out)                // [M*3] fp32
{
    const int tid  = threadIdx.x;
    const int wave = tid >> 6;
    const int lane = tid & 63;
    const int gw   = blockIdx.x * 4 + wave;
    const int nw   = gridDim.x * 4;
    const int g0   = lane * 8;

    float wp[3][8];
    float cpart[3];
    #pragma unroll
    for (int a = 0; a < 3; a++) {
        float cp = 0.f;
        #pragma unroll
        for (int j = 0; j < 8; j++) {
            const float w1 = Wf[a * 1024 + g0 + j];
            const float w2 = Wf[a * 1024 + 512 + g0 + j];
            wp[a][j] = w1 - w2 * INV_NM1;
            cp += colsum[g0 + j] * w2;
        }
        cpart[a] = cp;
    }
    float cfull[3];
    #pragma unroll
    for (int a = 0; a < 3; a++) {
        float v = cpart[a];
        #pragma unroll
        for (int off = 1; off < 64; off <<= 1)
            v += __shfl_xor(v, off, 64);
        cfull[a] = v * INV_NM1 + bfb[a];
    }

    for (int i = gw; i < M_DIM; i += nw) {
        const uint4 hv = ((const uint4*)(H + (size_t)i * N_DIM))[lane];
        const unsigned uu[4] = {hv.x, hv.y, hv.z, hv.w};
        float s0 = 0.f, s1 = 0.f, s2 = 0.f;
        #pragma unroll
        for (int q = 0; q < 4; q++) {
            const float f0 = __uint_as_float(uu[q] << 16);         // elem 2q
            const float f1 = __uint_as_float(uu[q] & 0xffff0000u); // elem 2q+1
            s0 += f0 * wp[0][2 * q] + f1 * wp[0][2 * q + 1];
            s1 += f0 * wp[1][2 * q] + f1 * wp[1][2 * q + 1];
            s2 += f0 * wp[2][2 * q] + f1 * wp[2][2 * q + 1];
        }
        #pragma unroll
        for (int off = 1; off < 64; off <<= 1) {
            s0 += __shfl_xor(s0, off, 64);
            s1 += __shfl_xor(s1, off, 64);
            s2 += __shfl_xor(s2, off, 64);
        }
        if (lane < 3) {
            float s = (lane == 0) ? s0 : ((lane == 1) ? s1 : s2);
            s += cfull[lane];
            s = s > 0.f ? s : 0.f;
            out[(size_t)i * 3 + lane] = s;
        }
    }
}

extern "C" void kernel_launch(void* const* d_in, const int* in_sizes, int n_in,
                              void* d_out, int out_size, void* d_ws, size_t ws_size,
                              hipStream_t stream) {
    // Select inputs by unique flat element counts (dtype-independent).
    const float* X   = (const float*)d_in[0];
    const float* Wh  = (const float*)d_in[1];
    const float* bh  = (const float*)d_in[2];
    const float* Wf  = (const float*)d_in[3];
    const float* bfb = (const float*)d_in[4];
    for (int i = 0; i < n_in; i++) {
        const float* p = (const float*)d_in[i];
        switch (in_sizes[i]) {
            case M_DIM * K_DIM: X   = p; break;   // 50331648
            case N_DIM * K_DIM: Wh  = p; break;   // 393216
            case N_DIM:         bh  = p; break;   // 512
            case 3 * 2 * N_DIM: Wf  = p; break;   // 3072
            case 3:             bfb = p; break;   // 3
            default: break;
        }
    }
    float* out = (float*)d_out;

    float* colsum     = (float*)d_ws;                              // 2 KB
    unsigned short* H = (unsigned short*)((char*)d_ws + 2048);     // 64 MB bf16

    hipMemsetAsync(colsum, 0, N_DIM * sizeof(float), stream);

    dim3 g1(N_DIM / 128, M_DIM / 128);   // (4, 512) = 2048 blocks
    gemm_h_kernel<<<g1, 256, 0, stream>>>(X, Wh, bh, H, colsum);

    head_kernel<<<1024, 256, 0, stream>>>(H, Wf, bfb, colsum, out);
}